// Round 3
// baseline (172.048 us; speedup 1.0000x reference)
//
#include <hip/hip_runtime.h>
#include <math.h>

#define F 128
#define OUT 128

typedef unsigned short ushort_t;
typedef __attribute__((ext_vector_type(8))) short bfrag;   // 8 bf16
typedef __attribute__((ext_vector_type(4))) float ffrag;   // 4 fp32 acc

__device__ __forceinline__ float bf_lo(unsigned int u) {
    return __uint_as_float(u << 16);
}
__device__ __forceinline__ float bf_hi(unsigned int u) {
    return __uint_as_float(u & 0xffff0000u);
}
__device__ __forceinline__ ushort_t f2bf(float f) {
    unsigned int x = __float_as_uint(f);
    unsigned int r = x + 0x7fffu + ((x >> 16) & 1u);
    return (ushort_t)(r >> 16);
}
__device__ __forceinline__ unsigned pk2(float lo, float hi) {
    return (unsigned)f2bf(lo) | ((unsigned)f2bf(hi) << 16);
}

// DPP rotate-add within a 16-lane row (VALU, no LDS pipe).
// row_ror:N ctrl = 0x120+N. Double-evaluates x: use with plain lvalues only.
#define DPP_ADD(x, ctrl) \
    ((x) + __int_as_float(__builtin_amdgcn_update_dpp( \
        0, __float_as_int(x), (ctrl), 0xf, 0xf, true)))

// ---------------------------------------------------------------------------
// prep: heterogeneous grid.
//  part0: feat fp32 -> abig[:, :128] bf16 (vector stores only).
//  part1: btp[j*128+k] = bf16(B[k][j]), B = [w1[:F] | w1[F:]] cols j=0..255.
//  part2: btf[j*256+k] = bf16(wf[k][j]), j=0..127.
//  part3: rowptr (dst sorted).
// ---------------------------------------------------------------------------
__global__ __launch_bounds__(256) void prep_kernel(
    const float* __restrict__ feat, const float* __restrict__ w1,
    const float* __restrict__ wf, const int* __restrict__ dst,
    ushort_t* __restrict__ abig,
    ushort_t* __restrict__ btp, ushort_t* __restrict__ btf,
    int* __restrict__ row_ptr, int n, int e, int nb0, int nb1, int nb2)
{
    const int b = blockIdx.x, t = threadIdx.x;
    if (b < nb0) {
        int i = b * 256 + t;
        if (i >= n * 16) return;
        int row = i >> 4, c = (i & 15) * 8;
        float4 a = *(const float4*)(feat + (size_t)row * F + c);
        float4 bb = *(const float4*)(feat + (size_t)row * F + c + 4);
        unsigned p0 = pk2(a.x, a.y), p1 = pk2(a.z, a.w);
        unsigned p2 = pk2(bb.x, bb.y), p3 = pk2(bb.z, bb.w);
        *(uint4*)(abig + (size_t)row * 256 + c) = make_uint4(p0, p1, p2, p3);
    } else if (b < nb0 + nb1) {
        int idx = (b - nb0) * 256 + t;                 // 0..32767
        int j = idx >> 7, k = idx & 127;
        float v = (j < F) ? w1[(size_t)k * F + j]
                          : w1[(size_t)(F + k) * F + (j - F)];
        btp[idx] = f2bf(v);
    } else if (b < nb0 + nb1 + nb2) {
        int idx = (b - nb0 - nb1) * 256 + t;           // 0..32767
        int j = idx >> 8, k = idx & 255;
        btf[idx] = f2bf(wf[(size_t)k * F + j]);
    } else {
        int i = (b - nb0 - nb1 - nb2) * 256 + t;
        if (i >= e) return;
        int d = dst[i];
        int prev = (i == 0) ? -1 : dst[i - 1];
        for (int v = prev + 1; v <= d; ++v) row_ptr[v] = i;
        if (i == e - 1) {
            for (int v = d + 1; v <= n; ++v) row_ptr[v] = e;
        }
    }
}

// ---------------------------------------------------------------------------
// G1 (proj): C[n x 256] = abig_feat(bf16) @ btp, epilogue exp(2*(c+bias)).
// Block = 64 rows x 256 cols, 4 waves (wave w: cols 64w..64w+63).
// cols<128 -> e_dst (+b1); cols>=128 -> espack (natural feature order,
// single uint4 store per 8 features).
// ---------------------------------------------------------------------------
#define PST 136
__global__ __launch_bounds__(256) void proj_gemm_kernel(
    const ushort_t* __restrict__ abig, const ushort_t* __restrict__ btp,
    const float* __restrict__ b1, ushort_t* __restrict__ e_dst,
    ushort_t* __restrict__ espack, int n)
{
    __shared__ ushort_t As[64 * PST];        // 17408 B
    __shared__ ushort_t Ep[4][16 * 80];      // 10240 B
    const int t = threadIdx.x;
    const int wv = t >> 6, lane = t & 63;
    const int lm = lane & 15, quad = lane >> 4;
    const int row0 = blockIdx.x * 64, col0 = wv * 64;

#pragma unroll
    for (int k = 0; k < 4; ++k) {            // 64 rows x 16 uint4, coalesced
        int l = k * 256 + t;
        int r = l >> 4, ch = l & 15;
        uint4 d = make_uint4(0, 0, 0, 0);
        if (row0 + r < n) d = *(const uint4*)(abig + (size_t)(row0 + r) * 256 + ch * 8);
        *(uint4*)(As + r * PST + ch * 8) = d;
    }
    __syncthreads();

    bfrag bfr[4][4];
#pragma unroll
    for (int ks = 0; ks < 4; ++ks)
#pragma unroll
        for (int ni = 0; ni < 4; ++ni)
            bfr[ks][ni] = *(const bfrag*)(btp + (size_t)(col0 + ni * 16 + lm) * 128
                                          + ks * 32 + quad * 8);

    ffrag acc[4][4];
#pragma unroll
    for (int mi = 0; mi < 4; ++mi)
#pragma unroll
        for (int ni = 0; ni < 4; ++ni) acc[mi][ni] = (ffrag){0.f, 0.f, 0.f, 0.f};

#pragma unroll
    for (int ks = 0; ks < 4; ++ks)
#pragma unroll
        for (int mi = 0; mi < 4; ++mi) {
            bfrag af = *(const bfrag*)(As + (mi * 16 + lm) * PST + ks * 32 + quad * 8);
#pragma unroll
            for (int ni = 0; ni < 4; ++ni)
                acc[mi][ni] = __builtin_amdgcn_mfma_f32_16x16x32_bf16(
                    af, bfr[ks][ni], acc[mi][ni], 0, 0, 0);
        }

    float bias[4];
#pragma unroll
    for (int ni = 0; ni < 4; ++ni)
        bias[ni] = (col0 < F) ? b1[col0 + ni * 16 + lm] : 0.f;

#pragma unroll
    for (int mi = 0; mi < 4; ++mi) {
        // compute-layout write into per-wave patch (conflict-free)
#pragma unroll
        for (int ni = 0; ni < 4; ++ni)
#pragma unroll
            for (int r = 0; r < 4; ++r)
                Ep[wv][(quad * 4 + r) * 80 + ni * 16 + lm] =
                    f2bf(__expf(2.f * (acc[mi][ni][r] + bias[ni])));
        // coalesced read-out: 2 passes x 8 rows x 8 lanes x 16B
#pragma unroll
        for (int ps = 0; ps < 2; ++ps) {
            int rl = ps * 8 + (lane >> 3), co = (lane & 7) * 8;
            uint4 vv = *(const uint4*)(&Ep[wv][rl * 80 + co]);
            int grow = row0 + mi * 16 + rl;
            if (grow < n) {
                if (col0 < F) {
                    *(uint4*)(e_dst + (size_t)grow * F + col0 + co) = vv;
                } else {
                    int f0 = col0 - F + co;   // multiple of 8
                    *(uint4*)(espack + (size_t)grow * F + f0) = vv;
                }
            }
        }
    }
}

// ---------------------------------------------------------------------------
// K2a (score): per-node softmax numerators. One 32-lane half-wave per node.
// Per edge: gather espack row (256 B, uint2/lane), p = sum_f w2_f/(1+ea*es),
// DPP reduce, g = exp2(K2 - 2*L2E*p). Stores g (fp32, streamed) and per-node
// inv = 1/sum(g). Gather working set = espack only (10 MB).
// ---------------------------------------------------------------------------
__global__ __launch_bounds__(256) void score_kernel(
    const ushort_t* __restrict__ e_dst, const ushort_t* __restrict__ espack,
    const int* __restrict__ src, const int* __restrict__ row_ptr,
    const float* __restrict__ w2, float* __restrict__ g_arr,
    float* __restrict__ sden, int n)
{
    const int v = (int)((blockIdx.x * 256u + threadIdx.x) >> 5);
    const int fl = threadIdx.x & 31;
    const int sbase = threadIdx.x & 32;

    const float4 wv4 = ((const float4*)w2)[fl];
    const float w0 = wv4.x, w1_ = wv4.y, w2_ = wv4.z, w3_ = wv4.w;
    float sw = w0 + w1_ + w2_ + w3_;
    float aw = fabsf(w0) + fabsf(w1_) + fabsf(w2_) + fabsf(w3_);
#pragma unroll
    for (int off = 16; off; off >>= 1) {
        sw += __shfl_xor(sw, off, 64);
        aw += __shfl_xor(aw, off, 64);
    }
    const float K = sw - aw;           // score - M = K - 2*pv  (always <= 0)
    const float L2E = 1.4426950408889634f;
    const float K2 = K * L2E;          // g = exp2(K2 - 2*L2E*p)

    if (v >= n) return;
    const int begin = row_ptr[v], end = row_ptr[v + 1];

    const uint2 ud = *(const uint2*)(e_dst + (size_t)v * F + fl * 4);
    const float ea0 = bf_lo(ud.x), ea1 = bf_hi(ud.x);
    const float ea2 = bf_lo(ud.y), ea3 = bf_hi(ud.y);

    const uint2* __restrict__ sp = (const uint2*)espack + fl;  // row = 32 uint2

    float s = 0.f;

    for (int cb = begin; cb < end; cb += 32) {
        const int clen = min(32, end - cb);
        const int sv = (fl < clen) ? src[cb + fl] : 0;
        int jj = 0;
        for (; jj + 4 <= clen; jj += 4) {
            uint2 u[4];
#pragma unroll
            for (int q = 0; q < 4; ++q) {
                const int sq = __shfl(sv, sbase + jj + q, 64);
                u[q] = sp[(size_t)sq * 32];
            }
            float p[4];
#pragma unroll
            for (int q = 0; q < 4; ++q) {
                float r;
                r = __builtin_amdgcn_rcpf(fmaf(ea0, bf_lo(u[q].x), 1.f)); p[q] = w0 * r;
                r = __builtin_amdgcn_rcpf(fmaf(ea1, bf_hi(u[q].x), 1.f)); p[q] = fmaf(w1_, r, p[q]);
                r = __builtin_amdgcn_rcpf(fmaf(ea2, bf_lo(u[q].y), 1.f)); p[q] = fmaf(w2_, r, p[q]);
                r = __builtin_amdgcn_rcpf(fmaf(ea3, bf_hi(u[q].y), 1.f)); p[q] = fmaf(w3_, r, p[q]);
            }
#pragma unroll
            for (int q = 0; q < 4; ++q) {
                p[q] = DPP_ADD(p[q], 0x121);     // row_ror:1
                p[q] = DPP_ADD(p[q], 0x122);     // row_ror:2
                p[q] = DPP_ADD(p[q], 0x124);     // row_ror:4
                p[q] = DPP_ADD(p[q], 0x128);     // row_ror:8
                p[q] += __shfl_xor(p[q], 16, 64);
            }
            float g0 = exp2f(fmaf(-2.f * L2E, p[0], K2));
            float g1 = exp2f(fmaf(-2.f * L2E, p[1], K2));
            float g2 = exp2f(fmaf(-2.f * L2E, p[2], K2));
            float g3 = exp2f(fmaf(-2.f * L2E, p[3], K2));
            s += (g0 + g1) + (g2 + g3);
            if (fl == 0) {
                g_arr[cb + jj + 0] = g0;
                g_arr[cb + jj + 1] = g1;
                g_arr[cb + jj + 2] = g2;
                g_arr[cb + jj + 3] = g3;
            }
        }
        for (; jj < clen; ++jj) {
            const int s0 = __shfl(sv, sbase + jj, 64);
            const uint2 u0 = sp[(size_t)s0 * 32];
            float r, p0;
            r = __builtin_amdgcn_rcpf(fmaf(ea0, bf_lo(u0.x), 1.f)); p0 = w0 * r;
            r = __builtin_amdgcn_rcpf(fmaf(ea1, bf_hi(u0.x), 1.f)); p0 = fmaf(w1_, r, p0);
            r = __builtin_amdgcn_rcpf(fmaf(ea2, bf_lo(u0.y), 1.f)); p0 = fmaf(w2_, r, p0);
            r = __builtin_amdgcn_rcpf(fmaf(ea3, bf_hi(u0.y), 1.f)); p0 = fmaf(w3_, r, p0);
            p0 = DPP_ADD(p0, 0x121);
            p0 = DPP_ADD(p0, 0x122);
            p0 = DPP_ADD(p0, 0x124);
            p0 = DPP_ADD(p0, 0x128);
            p0 += __shfl_xor(p0, 16, 64);
            const float gg = exp2f(fmaf(-2.f * L2E, p0, K2));
            s += gg;
            if (fl == 0) g_arr[cb + jj] = gg;
        }
    }

    const float inv = (end > begin) ? 1.f / s : 0.f;
    if (fl == 0) sden[v] = inv;
}

// ---------------------------------------------------------------------------
// K2b (aggregate): neigh[v] = inv * sum_e g_e * feat[src_e]. Gathers the
// feat half of abig rows (256 B, uint2/lane); g streamed (broadcast loads).
// Gather working set = feat half of abig (10 MB). Writes neigh to abig[:,128:].
// ---------------------------------------------------------------------------
__global__ __launch_bounds__(256) void agg_kernel(
    const int* __restrict__ src, const int* __restrict__ row_ptr,
    const float* __restrict__ g_arr, const float* __restrict__ sden,
    ushort_t* __restrict__ abig, int n)
{
    const int v = (int)((blockIdx.x * 256u + threadIdx.x) >> 5);
    const int fl = threadIdx.x & 31;
    const int sbase = threadIdx.x & 32;

    if (v >= n) return;
    const int begin = row_ptr[v], end = row_ptr[v + 1];
    const float inv = sden[v];

    const uint2* __restrict__ fp = (const uint2*)abig + fl;  // row = 64 uint2

    float a0 = 0.f, a1 = 0.f, a2 = 0.f, a3 = 0.f;

    for (int cb = begin; cb < end; cb += 32) {
        const int clen = min(32, end - cb);
        const int sv = (fl < clen) ? src[cb + fl] : 0;
        int jj = 0;
        for (; jj + 4 <= clen; jj += 4) {
            uint2 u[4];
            float g[4];
#pragma unroll
            for (int q = 0; q < 4; ++q) {
                const int sq = __shfl(sv, sbase + jj + q, 64);
                u[q] = fp[(size_t)sq * 64];
            }
#pragma unroll
            for (int q = 0; q < 4; ++q) g[q] = g_arr[cb + jj + q];
#pragma unroll
            for (int q = 0; q < 4; ++q) {
                a0 = fmaf(g[q], bf_lo(u[q].x), a0);
                a1 = fmaf(g[q], bf_hi(u[q].x), a1);
                a2 = fmaf(g[q], bf_lo(u[q].y), a2);
                a3 = fmaf(g[q], bf_hi(u[q].y), a3);
            }
        }
        for (; jj < clen; ++jj) {
            const int s0 = __shfl(sv, sbase + jj, 64);
            const uint2 u0 = fp[(size_t)s0 * 64];
            const float gg = g_arr[cb + jj];
            a0 = fmaf(gg, bf_lo(u0.x), a0);
            a1 = fmaf(gg, bf_hi(u0.x), a1);
            a2 = fmaf(gg, bf_lo(u0.y), a2);
            a3 = fmaf(gg, bf_hi(u0.y), a3);
        }
    }

    ushort4 o = make_ushort4(f2bf(a0 * inv), f2bf(a1 * inv),
                             f2bf(a2 * inv), f2bf(a3 * inv));
    *(ushort4*)(abig + (size_t)v * 256 + 128 + fl * 4) = o;
}

// ---------------------------------------------------------------------------
// G2 (out): out[n x 128] = abig(bf16, K=256) @ btf + bf.
// Block = 64 rows x 128 cols, 4 waves (wave w: cols 32w..32w+31).
// ---------------------------------------------------------------------------
#define OST 280
__global__ __launch_bounds__(256) void out_gemm_kernel(
    const ushort_t* __restrict__ abig, const ushort_t* __restrict__ btf,
    const float* __restrict__ bfv, float* __restrict__ out, int n)
{
    __shared__ ushort_t As[64 * OST];        // 35840 B
    const int t = threadIdx.x;
    const int wv = t >> 6, lane = t & 63;
    const int lm = lane & 15, quad = lane >> 4;
    const int row0 = blockIdx.x * 64, col0 = wv * 32;

#pragma unroll
    for (int k = 0; k < 8; ++k) {            // 64 rows x 32 uint4, coalesced
        int l = k * 256 + t;
        int r = l >> 5, ch = l & 31;
        uint4 d = make_uint4(0, 0, 0, 0);
        if (row0 + r < n) d = *(const uint4*)(abig + (size_t)(row0 + r) * 256 + ch * 8);
        *(uint4*)(As + r * OST + ch * 8) = d;
    }
    __syncthreads();

    bfrag bfr[8][2];
#pragma unroll
    for (int ks = 0; ks < 8; ++ks)
#pragma unroll
        for (int ni = 0; ni < 2; ++ni)
            bfr[ks][ni] = *(const bfrag*)(btf + (size_t)(col0 + ni * 16 + lm) * 256
                                          + ks * 32 + quad * 8);

    ffrag acc[4][2];
#pragma unroll
    for (int mi = 0; mi < 4; ++mi)
#pragma unroll
        for (int ni = 0; ni < 2; ++ni) acc[mi][ni] = (ffrag){0.f, 0.f, 0.f, 0.f};

#pragma unroll
    for (int ks = 0; ks < 8; ++ks)
#pragma unroll
        for (int mi = 0; mi < 4; ++mi) {
            bfrag af = *(const bfrag*)(As + (mi * 16 + lm) * OST + ks * 32 + quad * 8);
#pragma unroll
            for (int ni = 0; ni < 2; ++ni)
                acc[mi][ni] = __builtin_amdgcn_mfma_f32_16x16x32_bf16(
                    af, bfr[ks][ni], acc[mi][ni], 0, 0, 0);
        }

#pragma unroll
    for (int ni = 0; ni < 2; ++ni) {
        const int j = col0 + ni * 16 + lm;
        const float bb = bfv[j];
#pragma unroll
        for (int mi = 0; mi < 4; ++mi)
#pragma unroll
            for (int r = 0; r < 4; ++r) {
                int grow = row0 + mi * 16 + quad * 4 + r;
                if (grow < n) out[(size_t)grow * OUT + j] = acc[mi][ni][r] + bb;
            }
    }
}

// ---------------------------------------------------------------------------
extern "C" void kernel_launch(void* const* d_in, const int* in_sizes, int n_in,
                              void* d_out, int out_size, void* d_ws, size_t ws_size,
                              hipStream_t stream)
{
    const float* feat = (const float*)d_in[0];
    const int*   src  = (const int*)d_in[1];
    const int*   dst  = (const int*)d_in[2];
    const float* w1   = (const float*)d_in[3];
    const float* b1   = (const float*)d_in[4];
    const float* w2   = (const float*)d_in[5];
    const float* b2   = (const float*)d_in[6];  (void)b2; // cancels in softmax
    const float* wf   = (const float*)d_in[7];
    const float* bfv  = (const float*)d_in[8];
    float* out = (float*)d_out;

    const int n = in_sizes[0] / F;   // 40000
    const int e = in_sizes[1];       // 640000

    ushort_t* abig    = (ushort_t*)d_ws;                   // n*256 bf16 [feat|neigh]
    ushort_t* e_dst   = abig + (size_t)n * 256;            // n*128 bf16
    ushort_t* espack  = e_dst + (size_t)n * 128;           // n*128 bf16
    ushort_t* btp     = espack + (size_t)n * 128;          // 256*128 bf16 col-major
    ushort_t* btf     = btp + 32768;                       // 128*256 bf16 col-major
    int* row_ptr      = (int*)(btf + 32768);               // n+1
    float* g_arr      = (float*)(row_ptr + n + 1);         // e
    float* sden       = g_arr + e;                         // n

    const int nb0 = (n * 16 + 255) / 256;   // 2500
    const int nb1 = 128, nb2 = 128;
    const int nb3 = (e + 255) / 256;        // 2500

    prep_kernel<<<nb0 + nb1 + nb2 + nb3, 256, 0, stream>>>(
        feat, w1, wf, dst, abig, btp, btf, row_ptr, n, e, nb0, nb1, nb2);
    proj_gemm_kernel<<<(n + 63) / 64, 256, 0, stream>>>(
        abig, btp, b1, e_dst, espack, n);
    score_kernel<<<(n + 7) / 8, 256, 0, stream>>>(
        e_dst, espack, src, row_ptr, w2, g_arr, sden, n);
    agg_kernel<<<(n + 7) / 8, 256, 0, stream>>>(
        src, row_ptr, g_arr, sden, abig, n);
    out_gemm_kernel<<<(n + 63) / 64, 256, 0, stream>>>(abig, btf, bfv, out, n);
}

// Round 4
// 170.773 us; speedup vs baseline: 1.0075x; 1.0075x over previous
//
#include <hip/hip_runtime.h>
#include <math.h>

#define F 128
#define OUT 128

typedef unsigned short ushort_t;
typedef __attribute__((ext_vector_type(8))) short bfrag;   // 8 bf16
typedef __attribute__((ext_vector_type(4))) float ffrag;   // 4 fp32 acc

__device__ __forceinline__ float bf_lo(unsigned int u) {
    return __uint_as_float(u << 16);
}
__device__ __forceinline__ float bf_hi(unsigned int u) {
    return __uint_as_float(u & 0xffff0000u);
}
__device__ __forceinline__ ushort_t f2bf(float f) {
    unsigned int x = __float_as_uint(f);
    unsigned int r = x + 0x7fffu + ((x >> 16) & 1u);
    return (ushort_t)(r >> 16);
}
__device__ __forceinline__ unsigned pk2(float lo, float hi) {
    return (unsigned)f2bf(lo) | ((unsigned)f2bf(hi) << 16);
}

// DPP rotate-add within a 16-lane row (VALU, no LDS pipe).
// row_ror:N ctrl = 0x120+N. Double-evaluates x: use with plain lvalues only.
#define DPP_ADD(x, ctrl) \
    ((x) + __int_as_float(__builtin_amdgcn_update_dpp( \
        0, __float_as_int(x), (ctrl), 0xf, 0xf, true)))

// ---------------------------------------------------------------------------
// prep: heterogeneous grid.
//  part0: feat fp32 -> abig[:, :128] bf16 + srcpack feat-half (interleaved:
//         per 8-feature group: [es 0..3 | feat 0..3 | es 4..7 | feat 4..7]).
//  part1: btp[j*128+k] = bf16(B[k][j]), B = [w1[:F] | w1[F:]] cols j=0..255.
//  part2: btf[j*256+k] = bf16(wf[k][j]), j=0..127.
//  part3: rowptr (dst sorted).
// ---------------------------------------------------------------------------
__global__ __launch_bounds__(256) void prep_kernel(
    const float* __restrict__ feat, const float* __restrict__ w1,
    const float* __restrict__ wf, const int* __restrict__ dst,
    ushort_t* __restrict__ abig, ushort_t* __restrict__ srcpack,
    ushort_t* __restrict__ btp, ushort_t* __restrict__ btf,
    int* __restrict__ row_ptr, int n, int e, int nb0, int nb1, int nb2)
{
    const int b = blockIdx.x, t = threadIdx.x;
    if (b < nb0) {
        int i = b * 256 + t;
        if (i >= n * 16) return;
        int row = i >> 4, c = (i & 15) * 8;
        float4 a = *(const float4*)(feat + (size_t)row * F + c);
        float4 bb = *(const float4*)(feat + (size_t)row * F + c + 4);
        unsigned p0 = pk2(a.x, a.y), p1 = pk2(a.z, a.w);
        unsigned p2 = pk2(bb.x, bb.y), p3 = pk2(bb.z, bb.w);
        *(uint4*)(abig + (size_t)row * 256 + c) = make_uint4(p0, p1, p2, p3);
        *(uint2*)(srcpack + (size_t)row * 256 + c * 2 + 4) = make_uint2(p0, p1);
        *(uint2*)(srcpack + (size_t)row * 256 + c * 2 + 12) = make_uint2(p2, p3);
    } else if (b < nb0 + nb1) {
        int idx = (b - nb0) * 256 + t;                 // 0..32767
        int j = idx >> 7, k = idx & 127;
        float v = (j < F) ? w1[(size_t)k * F + j]
                          : w1[(size_t)(F + k) * F + (j - F)];
        btp[idx] = f2bf(v);
    } else if (b < nb0 + nb1 + nb2) {
        int idx = (b - nb0 - nb1) * 256 + t;           // 0..32767
        int j = idx >> 8, k = idx & 255;
        btf[idx] = f2bf(wf[(size_t)k * F + j]);
    } else {
        int i = (b - nb0 - nb1 - nb2) * 256 + t;
        if (i >= e) return;
        int d = dst[i];
        int prev = (i == 0) ? -1 : dst[i - 1];
        for (int v = prev + 1; v <= d; ++v) row_ptr[v] = i;
        if (i == e - 1) {
            for (int v = d + 1; v <= n; ++v) row_ptr[v] = e;
        }
    }
}

// ---------------------------------------------------------------------------
// G1 (proj): C[n x 256] = abig_feat(bf16) @ btp, epilogue exp(2*(c+bias)).
// Block = 64 rows x 256 cols, 4 waves (wave w: cols 64w..64w+63).
// cols<128 -> e_dst (+b1); cols>=128 -> srcpack e_src half (interleaved).
// ---------------------------------------------------------------------------
#define PST 136
__global__ __launch_bounds__(256) void proj_gemm_kernel(
    const ushort_t* __restrict__ abig, const ushort_t* __restrict__ btp,
    const float* __restrict__ b1, ushort_t* __restrict__ e_dst,
    ushort_t* __restrict__ srcpack, int n)
{
    __shared__ ushort_t As[64 * PST];        // 17408 B
    __shared__ ushort_t Ep[4][16 * 80];      // 10240 B
    const int t = threadIdx.x;
    const int wv = t >> 6, lane = t & 63;
    const int lm = lane & 15, quad = lane >> 4;
    const int row0 = blockIdx.x * 64, col0 = wv * 64;

#pragma unroll
    for (int k = 0; k < 4; ++k) {            // 64 rows x 16 uint4, coalesced
        int l = k * 256 + t;
        int r = l >> 4, ch = l & 15;
        uint4 d = make_uint4(0, 0, 0, 0);
        if (row0 + r < n) d = *(const uint4*)(abig + (size_t)(row0 + r) * 256 + ch * 8);
        *(uint4*)(As + r * PST + ch * 8) = d;
    }
    __syncthreads();

    bfrag bfr[4][4];
#pragma unroll
    for (int ks = 0; ks < 4; ++ks)
#pragma unroll
        for (int ni = 0; ni < 4; ++ni)
            bfr[ks][ni] = *(const bfrag*)(btp + (size_t)(col0 + ni * 16 + lm) * 128
                                          + ks * 32 + quad * 8);

    ffrag acc[4][4];
#pragma unroll
    for (int mi = 0; mi < 4; ++mi)
#pragma unroll
        for (int ni = 0; ni < 4; ++ni) acc[mi][ni] = (ffrag){0.f, 0.f, 0.f, 0.f};

#pragma unroll
    for (int ks = 0; ks < 4; ++ks)
#pragma unroll
        for (int mi = 0; mi < 4; ++mi) {
            bfrag af = *(const bfrag*)(As + (mi * 16 + lm) * PST + ks * 32 + quad * 8);
#pragma unroll
            for (int ni = 0; ni < 4; ++ni)
                acc[mi][ni] = __builtin_amdgcn_mfma_f32_16x16x32_bf16(
                    af, bfr[ks][ni], acc[mi][ni], 0, 0, 0);
        }

    float bias[4];
#pragma unroll
    for (int ni = 0; ni < 4; ++ni)
        bias[ni] = (col0 < F) ? b1[col0 + ni * 16 + lm] : 0.f;

#pragma unroll
    for (int mi = 0; mi < 4; ++mi) {
        // compute-layout write into per-wave patch (conflict-free)
#pragma unroll
        for (int ni = 0; ni < 4; ++ni)
#pragma unroll
            for (int r = 0; r < 4; ++r)
                Ep[wv][(quad * 4 + r) * 80 + ni * 16 + lm] =
                    f2bf(__expf(2.f * (acc[mi][ni][r] + bias[ni])));
        // coalesced read-out: 2 passes x 8 rows x 8 lanes x 16B
#pragma unroll
        for (int ps = 0; ps < 2; ++ps) {
            int rl = ps * 8 + (lane >> 3), co = (lane & 7) * 8;
            uint4 vv = *(const uint4*)(&Ep[wv][rl * 80 + co]);
            int grow = row0 + mi * 16 + rl;
            if (grow < n) {
                if (col0 < F) {
                    *(uint4*)(e_dst + (size_t)grow * F + col0 + co) = vv;
                } else {
                    int f0 = col0 - F + co;   // multiple of 8
                    *(uint2*)(srcpack + (size_t)grow * 256 + f0 * 2) =
                        make_uint2(vv.x, vv.y);
                    *(uint2*)(srcpack + (size_t)grow * 256 + f0 * 2 + 8) =
                        make_uint2(vv.z, vv.w);
                }
            }
        }
    }
}

// ---------------------------------------------------------------------------
// K2: fused score+softmax+aggregate. PERSISTENT half-waves: 1250 blocks,
// each 32-lane half-wave walks nodes v, v+10000, ... (amortizes setup,
// keeps SIMDs filled). Per edge: uniform load of src[e] (no bpermute),
// one uint4 gather (512 B row -> 4 es + 4 feat bf16 per lane), pair-rcp
// score (2 rcp/edge/lane instead of 4:  w_a/A + w_b/B = (w_a*B+w_b*A)/(A*B),
// A,B >= 1 so no hazard), DPP reduce, static softmax bound.
// Writes neigh bf16 to abig[:, 128:].
// ---------------------------------------------------------------------------
__global__ __launch_bounds__(256) void fused_kernel(
    const ushort_t* __restrict__ e_dst, const ushort_t* __restrict__ srcpack,
    const int* __restrict__ src, const int* __restrict__ row_ptr,
    const float* __restrict__ w2, ushort_t* __restrict__ abig, int n, int nhw)
{
    const int hw0 = (int)((blockIdx.x * 256u + threadIdx.x) >> 5);
    const int fl = threadIdx.x & 31;

    const float4 wv4 = ((const float4*)w2)[fl];
    const float w0 = wv4.x, w1_ = wv4.y, w2_ = wv4.z, w3_ = wv4.w;
    float sw = w0 + w1_ + w2_ + w3_;
    float aw = fabsf(w0) + fabsf(w1_) + fabsf(w2_) + fabsf(w3_);
#pragma unroll
    for (int off = 16; off; off >>= 1) {
        sw += __shfl_xor(sw, off, 64);
        aw += __shfl_xor(aw, off, 64);
    }
    const float K = sw - aw;           // score - M = K - 2*pv  (always <= 0)
    const float L2E = 1.4426950408889634f;
    const float K2 = K * L2E;          // g = exp2(K2 - 2*L2E*p)

    const uint4* __restrict__ sp = (const uint4*)srcpack + fl;  // row = 32 uint4

    for (int v = hw0; v < n; v += nhw) {
        const int begin = row_ptr[v], end = row_ptr[v + 1];

        const uint2 ud = *(const uint2*)(e_dst + (size_t)v * F + fl * 4);
        const float ea0 = bf_lo(ud.x), ea1 = bf_hi(ud.x);
        const float ea2 = bf_lo(ud.y), ea3 = bf_hi(ud.y);

        float s = 0.f, a0 = 0.f, a1 = 0.f, a2 = 0.f, a3 = 0.f;

        int ee = begin;
        for (; ee + 4 <= end; ee += 4) {
            uint4 u[4];
#pragma unroll
            for (int q = 0; q < 4; ++q) {
                const int sq = src[ee + q];            // uniform in half-wave
                u[q] = sp[(size_t)sq * 32];
            }
            float p[4];
#pragma unroll
            for (int q = 0; q < 4; ++q) {
                float A = fmaf(ea0, bf_lo(u[q].x), 1.f);
                float B = fmaf(ea1, bf_hi(u[q].x), 1.f);
                float C = fmaf(ea2, bf_lo(u[q].y), 1.f);
                float D = fmaf(ea3, bf_hi(u[q].y), 1.f);
                float nAB = fmaf(w0, B, w1_ * A);
                float nCD = fmaf(w2_, D, w3_ * C);
                float rAB = __builtin_amdgcn_rcpf(A * B);
                float rCD = __builtin_amdgcn_rcpf(C * D);
                p[q] = fmaf(nAB, rAB, nCD * rCD);
            }
#pragma unroll
            for (int q = 0; q < 4; ++q) {
                p[q] = DPP_ADD(p[q], 0x121);     // row_ror:1
                p[q] = DPP_ADD(p[q], 0x122);     // row_ror:2
                p[q] = DPP_ADD(p[q], 0x124);     // row_ror:4
                p[q] = DPP_ADD(p[q], 0x128);     // row_ror:8
                p[q] += __shfl_xor(p[q], 16, 64);
            }
            float g[4];
#pragma unroll
            for (int q = 0; q < 4; ++q)
                g[q] = exp2f(fmaf(-2.f * L2E, p[q], K2));
            s += (g[0] + g[1]) + (g[2] + g[3]);
#pragma unroll
            for (int q = 0; q < 4; ++q) {
                a0 = fmaf(g[q], bf_lo(u[q].z), a0);
                a1 = fmaf(g[q], bf_hi(u[q].z), a1);
                a2 = fmaf(g[q], bf_lo(u[q].w), a2);
                a3 = fmaf(g[q], bf_hi(u[q].w), a3);
            }
        }
        for (; ee < end; ++ee) {
            const int s0 = src[ee];
            const uint4 u0 = sp[(size_t)s0 * 32];
            float A = fmaf(ea0, bf_lo(u0.x), 1.f);
            float B = fmaf(ea1, bf_hi(u0.x), 1.f);
            float C = fmaf(ea2, bf_lo(u0.y), 1.f);
            float D = fmaf(ea3, bf_hi(u0.y), 1.f);
            float nAB = fmaf(w0, B, w1_ * A);
            float nCD = fmaf(w2_, D, w3_ * C);
            float rAB = __builtin_amdgcn_rcpf(A * B);
            float rCD = __builtin_amdgcn_rcpf(C * D);
            float p0 = fmaf(nAB, rAB, nCD * rCD);
            p0 = DPP_ADD(p0, 0x121);
            p0 = DPP_ADD(p0, 0x122);
            p0 = DPP_ADD(p0, 0x124);
            p0 = DPP_ADD(p0, 0x128);
            p0 += __shfl_xor(p0, 16, 64);
            const float g0 = exp2f(fmaf(-2.f * L2E, p0, K2));
            s += g0;
            a0 = fmaf(g0, bf_lo(u0.z), a0);
            a1 = fmaf(g0, bf_hi(u0.z), a1);
            a2 = fmaf(g0, bf_lo(u0.w), a2);
            a3 = fmaf(g0, bf_hi(u0.w), a3);
        }

        const float inv = (end > begin) ? 1.f / s : 0.f;
        ushort4 o = make_ushort4(f2bf(a0 * inv), f2bf(a1 * inv),
                                 f2bf(a2 * inv), f2bf(a3 * inv));
        *(ushort4*)(abig + (size_t)v * 256 + 128 + fl * 4) = o;
    }
}

// ---------------------------------------------------------------------------
// G2 (out): out[n x 128] = abig(bf16, K=256) @ btf + bf.
// Block = 64 rows x 128 cols, 4 waves (wave w: cols 32w..32w+31).
// ---------------------------------------------------------------------------
#define OST 280
__global__ __launch_bounds__(256) void out_gemm_kernel(
    const ushort_t* __restrict__ abig, const ushort_t* __restrict__ btf,
    const float* __restrict__ bfv, float* __restrict__ out, int n)
{
    __shared__ ushort_t As[64 * OST];        // 35840 B
    const int t = threadIdx.x;
    const int wv = t >> 6, lane = t & 63;
    const int lm = lane & 15, quad = lane >> 4;
    const int row0 = blockIdx.x * 64, col0 = wv * 32;

#pragma unroll
    for (int k = 0; k < 8; ++k) {            // 64 rows x 32 uint4, coalesced
        int l = k * 256 + t;
        int r = l >> 5, ch = l & 31;
        uint4 d = make_uint4(0, 0, 0, 0);
        if (row0 + r < n) d = *(const uint4*)(abig + (size_t)(row0 + r) * 256 + ch * 8);
        *(uint4*)(As + r * OST + ch * 8) = d;
    }
    __syncthreads();

    bfrag bfr[8][2];
#pragma unroll
    for (int ks = 0; ks < 8; ++ks)
#pragma unroll
        for (int ni = 0; ni < 2; ++ni)
            bfr[ks][ni] = *(const bfrag*)(btf + (size_t)(col0 + ni * 16 + lm) * 256
                                          + ks * 32 + quad * 8);

    ffrag acc[4][2];
#pragma unroll
    for (int mi = 0; mi < 4; ++mi)
#pragma unroll
        for (int ni = 0; ni < 2; ++ni) acc[mi][ni] = (ffrag){0.f, 0.f, 0.f, 0.f};

#pragma unroll
    for (int ks = 0; ks < 8; ++ks)
#pragma unroll
        for (int mi = 0; mi < 4; ++mi) {
            bfrag af = *(const bfrag*)(As + (mi * 16 + lm) * OST + ks * 32 + quad * 8);
#pragma unroll
            for (int ni = 0; ni < 2; ++ni)
                acc[mi][ni] = __builtin_amdgcn_mfma_f32_16x16x32_bf16(
                    af, bfr[ks][ni], acc[mi][ni], 0, 0, 0);
        }

#pragma unroll
    for (int ni = 0; ni < 2; ++ni) {
        const int j = col0 + ni * 16 + lm;
        const float bb = bfv[j];
#pragma unroll
        for (int mi = 0; mi < 4; ++mi)
#pragma unroll
            for (int r = 0; r < 4; ++r) {
                int grow = row0 + mi * 16 + quad * 4 + r;
                if (grow < n) out[(size_t)grow * OUT + j] = acc[mi][ni][r] + bb;
            }
    }
}

// ---------------------------------------------------------------------------
extern "C" void kernel_launch(void* const* d_in, const int* in_sizes, int n_in,
                              void* d_out, int out_size, void* d_ws, size_t ws_size,
                              hipStream_t stream)
{
    const float* feat = (const float*)d_in[0];
    const int*   src  = (const int*)d_in[1];
    const int*   dst  = (const int*)d_in[2];
    const float* w1   = (const float*)d_in[3];
    const float* b1   = (const float*)d_in[4];
    const float* w2   = (const float*)d_in[5];
    const float* b2   = (const float*)d_in[6];  (void)b2; // cancels in softmax
    const float* wf   = (const float*)d_in[7];
    const float* bfv  = (const float*)d_in[8];
    float* out = (float*)d_out;

    const int n = in_sizes[0] / F;   // 40000
    const int e = in_sizes[1];       // 640000

    ushort_t* abig    = (ushort_t*)d_ws;                   // n*256 bf16 [feat|neigh]
    ushort_t* e_dst   = abig + (size_t)n * 256;            // n*128 bf16
    ushort_t* srcpack = e_dst + (size_t)n * 128;           // n*256 bf16 interleaved
    ushort_t* btp     = srcpack + (size_t)n * 256;         // 256*128 bf16 col-major
    ushort_t* btf     = btp + 32768;                       // 128*256 bf16 col-major
    int* row_ptr      = (int*)(btf + 32768);               // n+1

    const int nb0 = (n * 16 + 255) / 256;   // 2500
    const int nb1 = 128, nb2 = 128;
    const int nb3 = (e + 255) / 256;        // 2500

    const int fblocks = 1250;               // persistent: 10000 half-waves
    const int nhw = fblocks * 8;

    prep_kernel<<<nb0 + nb1 + nb2 + nb3, 256, 0, stream>>>(
        feat, w1, wf, dst, abig, srcpack, btp, btf, row_ptr, n, e, nb0, nb1, nb2);
    proj_gemm_kernel<<<(n + 63) / 64, 256, 0, stream>>>(
        abig, btp, b1, e_dst, srcpack, n);
    fused_kernel<<<fblocks, 256, 0, stream>>>(
        e_dst, srcpack, src, row_ptr, w2, abig, n, nhw);
    out_gemm_kernel<<<(n + 63) / 64, 256, 0, stream>>>(abig, btf, bfv, out, n);
}

// Round 5
// 153.256 us; speedup vs baseline: 1.1226x; 1.1143x over previous
//
#include <hip/hip_runtime.h>
#include <math.h>

#define F 128
#define OUT 128

typedef unsigned short ushort_t;
typedef __attribute__((ext_vector_type(8))) short bfrag;   // 8 bf16
typedef __attribute__((ext_vector_type(4))) float ffrag;   // 4 fp32 acc
typedef __attribute__((ext_vector_type(2))) float fx2;     // 2 fp32

__device__ __forceinline__ float bf_lo(unsigned int u) {
    return __uint_as_float(u << 16);
}
__device__ __forceinline__ float bf_hi(unsigned int u) {
    return __uint_as_float(u & 0xffff0000u);
}
__device__ __forceinline__ ushort_t f2bf(float f) {
    unsigned int x = __float_as_uint(f);
    unsigned int r = x + 0x7fffu + ((x >> 16) & 1u);
    return (ushort_t)(r >> 16);
}
__device__ __forceinline__ unsigned pk2(float lo, float hi) {
    return (unsigned)f2bf(lo) | ((unsigned)f2bf(hi) << 16);
}

// DPP rotate-add within a 16-lane row (VALU, no LDS pipe).
// row_ror:N ctrl = 0x120+N. Double-evaluates x: use with plain lvalues only.
#define DPP_ADD(x, ctrl) \
    ((x) + __int_as_float(__builtin_amdgcn_update_dpp( \
        0, __float_as_int(x), (ctrl), 0xf, 0xf, true)))

// ---------------------------------------------------------------------------
// srcpack row layout (384 B per node, 128B-aligned):
//   bytes [0,256):   e_src = exp(2*proj_src) as bf16, natural feature order
//   bytes [256,384): feat as fp8 e4m3, natural feature order
// Lane fl of a half-wave covers features 4fl..4fl+3:
//   es  : uint2 at row + 8*fl
//   feat: uint  at row + 256 + 4*fl
// ---------------------------------------------------------------------------

// ---------------------------------------------------------------------------
// prep: heterogeneous grid.
//  part0: feat fp32 -> abig[:, :128] bf16 + srcpack fp8 half (HW cvt).
//  part1: btp[j*128+k] = bf16(B[k][j]), B = [w1[:F] | w1[F:]] cols j=0..255.
//  part2: btf[j*256+k] = bf16(wf[k][j]), j=0..127.
//  part3: rowptr (dst sorted).
// ---------------------------------------------------------------------------
__global__ __launch_bounds__(256) void prep_kernel(
    const float* __restrict__ feat, const float* __restrict__ w1,
    const float* __restrict__ wf, const int* __restrict__ dst,
    ushort_t* __restrict__ abig, ushort_t* __restrict__ srcpack,
    ushort_t* __restrict__ btp, ushort_t* __restrict__ btf,
    int* __restrict__ row_ptr, int n, int e, int nb0, int nb1, int nb2)
{
    const int b = blockIdx.x, t = threadIdx.x;
    if (b < nb0) {
        int i = b * 256 + t;
        if (i >= n * 16) return;
        int row = i >> 4, c = (i & 15) * 8;
        float4 a = *(const float4*)(feat + (size_t)row * F + c);
        float4 bb = *(const float4*)(feat + (size_t)row * F + c + 4);
        unsigned p0 = pk2(a.x, a.y), p1 = pk2(a.z, a.w);
        unsigned p2 = pk2(bb.x, bb.y), p3 = pk2(bb.z, bb.w);
        *(uint4*)(abig + (size_t)row * 256 + c) = make_uint4(p0, p1, p2, p3);
        // fp8 e4m3 encode (HW): bytes [f0,f1,f2,f3][f4,f5,f6,f7]
        unsigned w01 = (unsigned)__builtin_amdgcn_cvt_pk_fp8_f32(a.x, a.y, 0, false);
        w01 = (unsigned)__builtin_amdgcn_cvt_pk_fp8_f32(a.z, a.w, (int)w01, true);
        unsigned w23 = (unsigned)__builtin_amdgcn_cvt_pk_fp8_f32(bb.x, bb.y, 0, false);
        w23 = (unsigned)__builtin_amdgcn_cvt_pk_fp8_f32(bb.z, bb.w, (int)w23, true);
        *(uint2*)((char*)srcpack + (size_t)row * 384 + 256 + c) = make_uint2(w01, w23);
    } else if (b < nb0 + nb1) {
        int idx = (b - nb0) * 256 + t;                 // 0..32767
        int j = idx >> 7, k = idx & 127;
        float v = (j < F) ? w1[(size_t)k * F + j]
                          : w1[(size_t)(F + k) * F + (j - F)];
        btp[idx] = f2bf(v);
    } else if (b < nb0 + nb1 + nb2) {
        int idx = (b - nb0 - nb1) * 256 + t;           // 0..32767
        int j = idx >> 8, k = idx & 255;
        btf[idx] = f2bf(wf[(size_t)k * F + j]);
    } else {
        int i = (b - nb0 - nb1 - nb2) * 256 + t;
        if (i >= e) return;
        int d = dst[i];
        int prev = (i == 0) ? -1 : dst[i - 1];
        for (int v = prev + 1; v <= d; ++v) row_ptr[v] = i;
        if (i == e - 1) {
            for (int v = d + 1; v <= n; ++v) row_ptr[v] = e;
        }
    }
}

// ---------------------------------------------------------------------------
// G1 (proj): C[n x 256] = abig_feat(bf16) @ btp, epilogue exp(2*(c+bias)).
// Block = 64 rows x 256 cols, 4 waves (wave w: cols 64w..64w+63).
// cols<128 -> e_dst (+b1); cols>=128 -> srcpack es half (natural order).
// ---------------------------------------------------------------------------
#define PST 136
__global__ __launch_bounds__(256) void proj_gemm_kernel(
    const ushort_t* __restrict__ abig, const ushort_t* __restrict__ btp,
    const float* __restrict__ b1, ushort_t* __restrict__ e_dst,
    ushort_t* __restrict__ srcpack, int n)
{
    __shared__ ushort_t As[64 * PST];        // 17408 B
    __shared__ ushort_t Ep[4][16 * 80];      // 10240 B
    const int t = threadIdx.x;
    const int wv = t >> 6, lane = t & 63;
    const int lm = lane & 15, quad = lane >> 4;
    const int row0 = blockIdx.x * 64, col0 = wv * 64;

#pragma unroll
    for (int k = 0; k < 4; ++k) {            // 64 rows x 16 uint4, coalesced
        int l = k * 256 + t;
        int r = l >> 4, ch = l & 15;
        uint4 d = make_uint4(0, 0, 0, 0);
        if (row0 + r < n) d = *(const uint4*)(abig + (size_t)(row0 + r) * 256 + ch * 8);
        *(uint4*)(As + r * PST + ch * 8) = d;
    }
    __syncthreads();

    bfrag bfr[4][4];
#pragma unroll
    for (int ks = 0; ks < 4; ++ks)
#pragma unroll
        for (int ni = 0; ni < 4; ++ni)
            bfr[ks][ni] = *(const bfrag*)(btp + (size_t)(col0 + ni * 16 + lm) * 128
                                          + ks * 32 + quad * 8);

    ffrag acc[4][4];
#pragma unroll
    for (int mi = 0; mi < 4; ++mi)
#pragma unroll
        for (int ni = 0; ni < 4; ++ni) acc[mi][ni] = (ffrag){0.f, 0.f, 0.f, 0.f};

#pragma unroll
    for (int ks = 0; ks < 4; ++ks)
#pragma unroll
        for (int mi = 0; mi < 4; ++mi) {
            bfrag af = *(const bfrag*)(As + (mi * 16 + lm) * PST + ks * 32 + quad * 8);
#pragma unroll
            for (int ni = 0; ni < 4; ++ni)
                acc[mi][ni] = __builtin_amdgcn_mfma_f32_16x16x32_bf16(
                    af, bfr[ks][ni], acc[mi][ni], 0, 0, 0);
        }

    float bias[4];
#pragma unroll
    for (int ni = 0; ni < 4; ++ni)
        bias[ni] = (col0 < F) ? b1[col0 + ni * 16 + lm] : 0.f;

#pragma unroll
    for (int mi = 0; mi < 4; ++mi) {
        // compute-layout write into per-wave patch (conflict-free)
#pragma unroll
        for (int ni = 0; ni < 4; ++ni)
#pragma unroll
            for (int r = 0; r < 4; ++r)
                Ep[wv][(quad * 4 + r) * 80 + ni * 16 + lm] =
                    f2bf(__expf(2.f * (acc[mi][ni][r] + bias[ni])));
        // coalesced read-out: 2 passes x 8 rows x 8 lanes x 16B
#pragma unroll
        for (int ps = 0; ps < 2; ++ps) {
            int rl = ps * 8 + (lane >> 3), co = (lane & 7) * 8;
            uint4 vv = *(const uint4*)(&Ep[wv][rl * 80 + co]);
            int grow = row0 + mi * 16 + rl;
            if (grow < n) {
                if (col0 < F) {
                    *(uint4*)(e_dst + (size_t)grow * F + col0 + co) = vv;
                } else {
                    int f0 = col0 - F + co;   // multiple of 8
                    *(uint4*)((char*)srcpack + (size_t)grow * 384 + (size_t)f0 * 2) = vv;
                }
            }
        }
    }
}

// ---------------------------------------------------------------------------
// K2: fused score+softmax+aggregate. One 32-lane half-wave per node; per
// edge: one uint2 gather (es bf16, 256 B/row) + one uint gather (feat fp8,
// 128 B/row) -> 384 B/edge (was 512). Pair-rcp score (2 rcp/edge/lane:
// w_a/A + w_b/B = (w_a*B+w_b*A)*rcp(A*B), A,B>=1), DPP reduce, static
// softmax bound M = b2 + sum|w2|. feat decoded with HW v_cvt_pk_f32_fp8.
// Writes neigh bf16 to abig[:, 128:].
// ---------------------------------------------------------------------------
__global__ __launch_bounds__(256) void fused_kernel(
    const ushort_t* __restrict__ e_dst, const ushort_t* __restrict__ srcpack,
    const int* __restrict__ src, const int* __restrict__ row_ptr,
    const float* __restrict__ w2, ushort_t* __restrict__ abig, int n)
{
    const int v = (int)((blockIdx.x * 256u + threadIdx.x) >> 5);
    const int fl = threadIdx.x & 31;
    const int sbase = threadIdx.x & 32;

    const float4 wv4 = ((const float4*)w2)[fl];
    const float w0 = wv4.x, w1_ = wv4.y, w2_ = wv4.z, w3_ = wv4.w;
    float sw = w0 + w1_ + w2_ + w3_;
    float aw = fabsf(w0) + fabsf(w1_) + fabsf(w2_) + fabsf(w3_);
#pragma unroll
    for (int off = 16; off; off >>= 1) {
        sw += __shfl_xor(sw, off, 64);
        aw += __shfl_xor(aw, off, 64);
    }
    const float K = sw - aw;           // score - M = K - 2*pv  (always <= 0)
    const float L2E = 1.4426950408889634f;
    const float K2 = K * L2E;          // g = exp2(K2 - 2*L2E*p)

    if (v >= n) return;
    const int begin = row_ptr[v], end = row_ptr[v + 1];

    const uint2 ud = *(const uint2*)(e_dst + (size_t)v * F + fl * 4);
    const float ea0 = bf_lo(ud.x), ea1 = bf_hi(ud.x);
    const float ea2 = bf_lo(ud.y), ea3 = bf_hi(ud.y);

    const char* __restrict__ spb = (const char*)srcpack;

    float s = 0.f, a0 = 0.f, a1 = 0.f, a2 = 0.f, a3 = 0.f;

    for (int cb = begin; cb < end; cb += 32) {
        const int clen = min(32, end - cb);
        const int sv = (fl < clen) ? src[cb + fl] : 0;
        int jj = 0;
        for (; jj + 4 <= clen; jj += 4) {
            uint2 u[4];
            unsigned vf[4];
#pragma unroll
            for (int q = 0; q < 4; ++q) {
                const int sq = __shfl(sv, sbase + jj + q, 64);
                const char* rb = spb + (size_t)sq * 384;
                u[q] = ((const uint2*)rb)[fl];
                vf[q] = ((const unsigned*)(rb + 256))[fl];
            }
            float p[4];
#pragma unroll
            for (int q = 0; q < 4; ++q) {
                float A = fmaf(ea0, bf_lo(u[q].x), 1.f);
                float B = fmaf(ea1, bf_hi(u[q].x), 1.f);
                float C = fmaf(ea2, bf_lo(u[q].y), 1.f);
                float D = fmaf(ea3, bf_hi(u[q].y), 1.f);
                float nAB = fmaf(w0, B, w1_ * A);
                float nCD = fmaf(w2_, D, w3_ * C);
                float rAB = __builtin_amdgcn_rcpf(A * B);
                float rCD = __builtin_amdgcn_rcpf(C * D);
                p[q] = fmaf(nAB, rAB, nCD * rCD);
            }
#pragma unroll
            for (int q = 0; q < 4; ++q) {
                p[q] = DPP_ADD(p[q], 0x121);     // row_ror:1
                p[q] = DPP_ADD(p[q], 0x122);     // row_ror:2
                p[q] = DPP_ADD(p[q], 0x124);     // row_ror:4
                p[q] = DPP_ADD(p[q], 0x128);     // row_ror:8
                p[q] += __shfl_xor(p[q], 16, 64);
            }
            float g[4];
#pragma unroll
            for (int q = 0; q < 4; ++q)
                g[q] = exp2f(fmaf(-2.f * L2E, p[q], K2));
            s += (g[0] + g[1]) + (g[2] + g[3]);
#pragma unroll
            for (int q = 0; q < 4; ++q) {
                fx2 lo = __builtin_amdgcn_cvt_pk_f32_fp8((int)vf[q], false);
                fx2 hi = __builtin_amdgcn_cvt_pk_f32_fp8((int)vf[q], true);
                a0 = fmaf(g[q], lo[0], a0);
                a1 = fmaf(g[q], lo[1], a1);
                a2 = fmaf(g[q], hi[0], a2);
                a3 = fmaf(g[q], hi[1], a3);
            }
        }
        for (; jj < clen; ++jj) {
            const int s0 = __shfl(sv, sbase + jj, 64);
            const char* rb = spb + (size_t)s0 * 384;
            const uint2 u0 = ((const uint2*)rb)[fl];
            const unsigned vf0 = ((const unsigned*)(rb + 256))[fl];
            float A = fmaf(ea0, bf_lo(u0.x), 1.f);
            float B = fmaf(ea1, bf_hi(u0.x), 1.f);
            float C = fmaf(ea2, bf_lo(u0.y), 1.f);
            float D = fmaf(ea3, bf_hi(u0.y), 1.f);
            float nAB = fmaf(w0, B, w1_ * A);
            float nCD = fmaf(w2_, D, w3_ * C);
            float rAB = __builtin_amdgcn_rcpf(A * B);
            float rCD = __builtin_amdgcn_rcpf(C * D);
            float p0 = fmaf(nAB, rAB, nCD * rCD);
            p0 = DPP_ADD(p0, 0x121);
            p0 = DPP_ADD(p0, 0x122);
            p0 = DPP_ADD(p0, 0x124);
            p0 = DPP_ADD(p0, 0x128);
            p0 += __shfl_xor(p0, 16, 64);
            const float g0 = exp2f(fmaf(-2.f * L2E, p0, K2));
            s += g0;
            fx2 lo = __builtin_amdgcn_cvt_pk_f32_fp8((int)vf0, false);
            fx2 hi = __builtin_amdgcn_cvt_pk_f32_fp8((int)vf0, true);
            a0 = fmaf(g0, lo[0], a0);
            a1 = fmaf(g0, lo[1], a1);
            a2 = fmaf(g0, hi[0], a2);
            a3 = fmaf(g0, hi[1], a3);
        }
    }

    const float inv = (end > begin) ? 1.f / s : 0.f;
    ushort4 o = make_ushort4(f2bf(a0 * inv), f2bf(a1 * inv),
                             f2bf(a2 * inv), f2bf(a3 * inv));
    *(ushort4*)(abig + (size_t)v * 256 + 128 + fl * 4) = o;
}

// ---------------------------------------------------------------------------
// G2 (out): out[n x 128] = abig(bf16, K=256) @ btf + bf.
// Block = 64 rows x 128 cols, 4 waves (wave w: cols 32w..32w+31).
// ---------------------------------------------------------------------------
#define OST 280
__global__ __launch_bounds__(256) void out_gemm_kernel(
    const ushort_t* __restrict__ abig, const ushort_t* __restrict__ btf,
    const float* __restrict__ bfv, float* __restrict__ out, int n)
{
    __shared__ ushort_t As[64 * OST];        // 35840 B
    const int t = threadIdx.x;
    const int wv = t >> 6, lane = t & 63;
    const int lm = lane & 15, quad = lane >> 4;
    const int row0 = blockIdx.x * 64, col0 = wv * 32;

#pragma unroll
    for (int k = 0; k < 8; ++k) {            // 64 rows x 32 uint4, coalesced
        int l = k * 256 + t;
        int r = l >> 5, ch = l & 31;
        uint4 d = make_uint4(0, 0, 0, 0);
        if (row0 + r < n) d = *(const uint4*)(abig + (size_t)(row0 + r) * 256 + ch * 8);
        *(uint4*)(As + r * OST + ch * 8) = d;
    }
    __syncthreads();

    bfrag bfr[8][2];
#pragma unroll
    for (int ks = 0; ks < 8; ++ks)
#pragma unroll
        for (int ni = 0; ni < 2; ++ni)
            bfr[ks][ni] = *(const bfrag*)(btf + (size_t)(col0 + ni * 16 + lm) * 256
                                          + ks * 32 + quad * 8);

    ffrag acc[4][2];
#pragma unroll
    for (int mi = 0; mi < 4; ++mi)
#pragma unroll
        for (int ni = 0; ni < 2; ++ni) acc[mi][ni] = (ffrag){0.f, 0.f, 0.f, 0.f};

#pragma unroll
    for (int ks = 0; ks < 8; ++ks)
#pragma unroll
        for (int mi = 0; mi < 4; ++mi) {
            bfrag af = *(const bfrag*)(As + (mi * 16 + lm) * OST + ks * 32 + quad * 8);
#pragma unroll
            for (int ni = 0; ni < 2; ++ni)
                acc[mi][ni] = __builtin_amdgcn_mfma_f32_16x16x32_bf16(
                    af, bfr[ks][ni], acc[mi][ni], 0, 0, 0);
        }

#pragma unroll
    for (int ni = 0; ni < 2; ++ni) {
        const int j = col0 + ni * 16 + lm;
        const float bb = bfv[j];
#pragma unroll
        for (int mi = 0; mi < 4; ++mi)
#pragma unroll
            for (int r = 0; r < 4; ++r) {
                int grow = row0 + mi * 16 + quad * 4 + r;
                if (grow < n) out[(size_t)grow * OUT + j] = acc[mi][ni][r] + bb;
            }
    }
}

// ---------------------------------------------------------------------------
extern "C" void kernel_launch(void* const* d_in, const int* in_sizes, int n_in,
                              void* d_out, int out_size, void* d_ws, size_t ws_size,
                              hipStream_t stream)
{
    const float* feat = (const float*)d_in[0];
    const int*   src  = (const int*)d_in[1];
    const int*   dst  = (const int*)d_in[2];
    const float* w1   = (const float*)d_in[3];
    const float* b1   = (const float*)d_in[4];
    const float* w2   = (const float*)d_in[5];
    const float* b2   = (const float*)d_in[6];  (void)b2; // cancels in softmax
    const float* wf   = (const float*)d_in[7];
    const float* bfv  = (const float*)d_in[8];
    float* out = (float*)d_out;

    const int n = in_sizes[0] / F;   // 40000
    const int e = in_sizes[1];       // 640000

    ushort_t* abig    = (ushort_t*)d_ws;                   // n*256 bf16 [feat|neigh]
    ushort_t* e_dst   = abig + (size_t)n * 256;            // n*128 bf16
    ushort_t* srcpack = e_dst + (size_t)n * 128;           // n*192 (384 B rows)
    ushort_t* btp     = srcpack + (size_t)n * 192;         // 256*128 bf16 col-major
    ushort_t* btf     = btp + 32768;                       // 128*256 bf16 col-major
    int* row_ptr      = (int*)(btf + 32768);               // n+1

    const int nb0 = (n * 16 + 255) / 256;   // 2500
    const int nb1 = 128, nb2 = 128;
    const int nb3 = (e + 255) / 256;        // 2500

    prep_kernel<<<nb0 + nb1 + nb2 + nb3, 256, 0, stream>>>(
        feat, w1, wf, dst, abig, srcpack, btp, btf, row_ptr, n, e, nb0, nb1, nb2);
    proj_gemm_kernel<<<(n + 63) / 64, 256, 0, stream>>>(
        abig, btp, b1, e_dst, srcpack, n);
    fused_kernel<<<(n + 7) / 8, 256, 0, stream>>>(
        e_dst, srcpack, src, row_ptr, w2, abig, n);
    out_gemm_kernel<<<(n + 63) / 64, 256, 0, stream>>>(abig, btf, bfv, out, n);
}